// Round 7
// baseline (59.291 us; speedup 1.0000x reference)
//
#include <hip/hip_runtime.h>

// TemporalCorrelation as band-GEMM on MFMA — round-5 structure with the
// K-loop __syncthreads() replaced by {s_waitcnt lgkmcnt(0); s_barrier}.
// HIP's __syncthreads lowers to vmcnt(0)+lgkmcnt(0) drain, which was killing
// the depth-4 global->reg prefetch (loads forced to complete at every
// barrier). Raw barrier + lgkmcnt-only wait keeps prefetch loads in flight
// across barriers (T3/T4 counted-vmcnt mechanism, m194-m201 pattern).
// out[b,o,t] = <f1[b,:,t], f2[b,:,clamp(t+o-10)]> / (||f1[:,t]|| ||f2[:,t']||)

constexpr int B  = 8;
constexpr int C  = 1024;
constexpr int T  = 4096;
constexpr int NO = 21;
constexpr int MD = 10;

typedef __attribute__((ext_vector_type(8))) short short8;
typedef __attribute__((ext_vector_type(4))) float f32x4;

__device__ inline unsigned bf16rne(float f) {
    unsigned u = __float_as_uint(f);
    return (u + 0x7FFFu + ((u >> 16) & 1u)) >> 16;   // RNE bf16 in low 16
}
__device__ inline unsigned pack2(float lo, float hi) {
    return bf16rne(lo) | (bf16rne(hi) << 16);
}

// Workgroup barrier that publishes LDS (lgkmcnt) but does NOT drain vmcnt:
// global prefetch loads into private VGPRs stay in flight across it.
__device__ inline void wg_barrier_lds() {
    asm volatile("s_waitcnt lgkmcnt(0)" ::: "memory");
    __builtin_amdgcn_s_barrier();
}

struct Regs { float4 a0, a1, b0, b0b, b1, b1b; };

__global__ __launch_bounds__(256, 2)
void corr_mfma(const float* __restrict__ f1, const float* __restrict__ f2,
               float* __restrict__ out)
{
    __shared__ short8 stgv[2][640];          // 2 x 5120 hw = 20 KB
    __shared__ float  sq1buf[64][17];
    __shared__ float  sq2buf[4][96];
    __shared__ float  inv1L[64];
    __shared__ float  inv2L[96];
    __shared__ float  outT[NO][68];

    const int sb   = (int)blockIdx.x;
    const int flat = (sb & 7) * 64 + (sb >> 3);    // XCD swizzle (512%8==0)
    const int b    = flat >> 6;
    const int t0   = (flat & 63) * 64;

    const int tid  = (int)threadIdx.x;
    const int lane = tid & 63;
    const int w    = tid >> 6;                     // wave id = M-tile id

    // ---- staging maps (constant across chunks) ----
    const int u1 = tid & 15;                       // f1 t-run (4 cols)
    const int q1 = tid >> 4;                       // f1 c-pair: rows 2q1,2q1+1
    const int r2 = tid & 15;                       // f2 window run (4 cols)
    const int q2 = tid >> 4;                       // f2 c-pair
    const bool x2 = (r2 < 8);                      // also stages run 16+r2

    const float* f1p = f1 + ((size_t)b * C + 2 * q1) * T + t0 + 4 * u1;
    const float* f2p = f2 + ((size_t)b * C + 2 * q2) * T;
    const int cA = min(max(t0 - 16 + 4 * r2,        0), T - 4);  // clamped src
    const int cB = min(max(t0 - 16 + 4 * (16 + r2), 0), T - 4);

    // store hw offsets: tile=[16t][32c], elem(t,c) at t*32 + slot'*8 + (c&7),
    // slot' = ((c>>3) + (t>>2)) & 3. Writes step +32 hw per t (i=0..3).
    const int f1hw = (u1 >> 2) * 512 + 4 * (u1 & 3) * 32
                   + ((((q1 >> 2) + (u1 & 3)) & 3) << 3) + 2 * (q1 & 3);
    const int f2hwA = 2048 + (r2 >> 2) * 512 + 4 * (r2 & 3) * 32
                    + ((((q2 >> 2) + (r2 & 3)) & 3) << 3) + 2 * (q2 & 3);
    const int f2hwB = f2hwA + 2048;               // run 16+r2: tile +4

    // fragment read offset: lane wants t=lane&15, c-slot=lane>>4
    const int ft  = lane & 15;
    const int fhw = ft * 32 + ((((lane >> 4) + (ft >> 2)) & 3) << 3);

    float sq1[4]  = {0.f, 0.f, 0.f, 0.f};
    float sq2a[4] = {0.f, 0.f, 0.f, 0.f};
    float sq2b[4] = {0.f, 0.f, 0.f, 0.f};
    f32x4 acc0 = {0.f,0.f,0.f,0.f}, acc1 = {0.f,0.f,0.f,0.f}, acc2 = {0.f,0.f,0.f,0.f};

    auto load_chunk = [&](int k) {
        Regs r; const size_t o = (size_t)k * 32 * T;
        r.a0  = *(const float4*)(f1p + o);
        r.a1  = *(const float4*)(f1p + o + T);
        r.b0  = *(const float4*)(f2p + o + cA);
        r.b0b = *(const float4*)(f2p + o + cA + T);
        if (x2) {
            r.b1  = *(const float4*)(f2p + o + cB);
            r.b1b = *(const float4*)(f2p + o + cB + T);
        }
        return r;
    };
    auto commit = [&](const Regs& r, int buf) {
        unsigned short* S = (unsigned short*)&stgv[buf][0];
        const float* a0 = (const float*)&r.a0;  const float* a1  = (const float*)&r.a1;
        const float* b0 = (const float*)&r.b0;  const float* b0b = (const float*)&r.b0b;
        const float* b1 = (const float*)&r.b1;  const float* b1b = (const float*)&r.b1b;
#pragma unroll
        for (int i = 0; i < 4; ++i) {
            *(unsigned*)&S[f1hw  + 32 * i] = pack2(a0[i], a1[i]);
            *(unsigned*)&S[f2hwA + 32 * i] = pack2(b0[i], b0b[i]);
            sq1[i]  += a0[i] * a0[i] + a1[i] * a1[i];
            sq2a[i] += b0[i] * b0[i] + b0b[i] * b0b[i];
        }
        if (x2) {
#pragma unroll
            for (int i = 0; i < 4; ++i) {
                *(unsigned*)&S[f2hwB + 32 * i] = pack2(b1[i], b1b[i]);
                sq2b[i] += b1[i] * b1[i] + b1b[i] * b1b[i];
            }
        }
    };
    auto compute = [&](int buf) {
        const unsigned short* S = (const unsigned short*)&stgv[buf][0];
        short8 af  = *(const short8*)&S[w * 512 + fhw];
        short8 bf0 = *(const short8*)&S[2048 + (w + 0) * 512 + fhw];
        short8 bf1 = *(const short8*)&S[2048 + (w + 1) * 512 + fhw];
        short8 bf2 = *(const short8*)&S[2048 + (w + 2) * 512 + fhw];
        acc0 = __builtin_amdgcn_mfma_f32_16x16x32_bf16(af, bf0, acc0, 0, 0, 0);
        acc1 = __builtin_amdgcn_mfma_f32_16x16x32_bf16(af, bf1, acc1, 0, 0, 0);
        acc2 = __builtin_amdgcn_mfma_f32_16x16x32_bf16(af, bf2, acc2, 0, 0, 0);
    };

    // ---- depth-4 pipelined K-loop (4 reg buffers, 2 LDS buffers) ----
    // Barriers publish LDS only; global prefetch stays in flight across them.
    Regs R0 = load_chunk(0), R1 = load_chunk(1),
         R2 = load_chunk(2), R3 = load_chunk(3);
    for (int k = 0; k < 32; k += 4) {
        commit(R0, 0);
        wg_barrier_lds();
        if (k + 4 < 32) R0 = load_chunk(k + 4);
        compute(0);
        commit(R1, 1);
        wg_barrier_lds();
        if (k + 5 < 32) R1 = load_chunk(k + 5);
        compute(1);
        commit(R2, 0);
        wg_barrier_lds();
        if (k + 6 < 32) R2 = load_chunk(k + 6);
        compute(0);
        commit(R3, 1);
        wg_barrier_lds();
        if (k + 7 < 32) R3 = load_chunk(k + 7);
        compute(1);
    }

    // ---- norms ----
#pragma unroll
    for (int e = 0; e < 4; ++e) sq1buf[4 * u1 + e][q1] = sq1[e];
#pragma unroll
    for (int i = 0; i < 4; ++i) {
        sq2a[i] += __shfl_xor(sq2a[i], 16, 64);
        sq2a[i] += __shfl_xor(sq2a[i], 32, 64);
        sq2b[i] += __shfl_xor(sq2b[i], 16, 64);
        sq2b[i] += __shfl_xor(sq2b[i], 32, 64);
    }
    if (lane < 16) {
#pragma unroll
        for (int i = 0; i < 4; ++i) sq2buf[w][4 * lane + i] = sq2a[i];
    }
    if (lane < 8) {
#pragma unroll
        for (int i = 0; i < 4; ++i) sq2buf[w][64 + 4 * lane + i] = sq2b[i];
    }
    __syncthreads();
    if (tid < 64) {
        float s = 0.f;
#pragma unroll
        for (int g = 0; g < 16; ++g) s += sq1buf[tid][g];
        inv1L[tid] = 1.f / fmaxf(sqrtf(s), 1e-12f);
    } else if (tid < 160) {
        const int f = tid - 64;
        float s = sq2buf[0][f] + sq2buf[1][f] + sq2buf[2][f] + sq2buf[3][f];
        inv2L[f] = 1.f / fmaxf(sqrtf(s), 1e-12f);
    }
    __syncthreads();

    // ---- epilogue: band elems -> outT with clamp-redirect, then coalesced ----
    const int m0  = t0 + w * 16;
    const int cr  = lane & 15;            // N-col within tile
    const int rr4 = (lane >> 4) * 4;      // M-row base
#define EPI(nt, A)                                                          \
    {                                                                       \
        const int tp = t0 - 16 + (w + (nt)) * 16 + cr;                      \
        _Pragma("unroll")                                                   \
        for (int r = 0; r < 4; ++r) {                                       \
            const int t = m0 + rr4 + r;                                     \
            const int d = tp - t;                                           \
            if (tp >= 0 && tp < T && d >= -MD && d <= MD) {                 \
                const float val = (A)[r] * inv1L[t - t0] * inv2L[tp - t0 + 16]; \
                const int on  = d + MD;                                     \
                const int olo = (tp == 0)     ? 0      : on;                \
                const int ohi = (tp == T - 1) ? NO - 1 : on;                \
                for (int o = olo; o <= ohi; ++o) outT[o][t - t0] = val;     \
            }                                                               \
        }                                                                   \
    }
    EPI(0, acc0) EPI(1, acc1) EPI(2, acc2)
#undef EPI
    __syncthreads();

    for (int task = tid; task < NO * 16; task += 256) {
        const int o  = task >> 4;
        const int t4 = (task & 15) * 4;
        const float4 v = *(const float4*)&outT[o][t4];
        *(float4*)(out + ((size_t)b * NO + o) * T + t0 + t4) = v;
    }
}

extern "C" void kernel_launch(void* const* d_in, const int* in_sizes, int n_in,
                              void* d_out, int out_size, void* d_ws, size_t ws_size,
                              hipStream_t stream)
{
    const float* f1 = (const float*)d_in[0];
    const float* f2 = (const float*)d_in[1];
    (void)d_ws; (void)ws_size;
    corr_mfma<<<dim3(512), dim3(256), 0, stream>>>(f1, f2, (float*)d_out);
}

// Round 8
// 56.071 us; speedup vs baseline: 1.0574x; 1.0574x over previous
//
#include <hip/hip_runtime.h>

// TemporalCorrelation as band-GEMM on MFMA, channel-split ACROSS BLOCKS.
// Round-3 verified block structure (4 waves, 64-col tile, depth-2 pipeline,
// __syncthreads); each block handles 256 of 1024 channels and writes raw
// partial dots + partial sums-of-squares to workspace. A fused finalize
// kernel reduces partials, computes norms, applies clamp-redirect, writes out.
// Rationale: rounds 3-6 show a barrier-convergence latency stall at 2
// blocks/CU; this gives 5 independent blocks/CU (20 waves) to hide latency.

constexpr int B   = 8;
constexpr int C   = 1024;
constexpr int T   = 4096;
constexpr int NO  = 21;
constexpr int MD  = 10;
constexpr int CS  = 4;          // channel-split factor (across blocks)
constexpr int CPS = C / CS;     // 256 channels per block
constexpr int NCHK = CPS / 32;  // 8 K-chunks per block

typedef __attribute__((ext_vector_type(8))) short short8;
typedef __attribute__((ext_vector_type(4))) float f32x4;

__device__ inline unsigned bf16rne(float f) {
    unsigned u = __float_as_uint(f);
    return (u + 0x7FFFu + ((u >> 16) & 1u)) >> 16;   // RNE bf16 in low 16
}
__device__ inline unsigned pack2(float lo, float hi) {
    return bf16rne(lo) | (bf16rne(hi) << 16);
}

struct Regs { float4 a0, a1, b0, b0b, b1, b1b; };

__global__ __launch_bounds__(256)
void corr_mfma(const float* __restrict__ f1, const float* __restrict__ f2,
               float* __restrict__ dots, float* __restrict__ s1p,
               float* __restrict__ s2p)
{
    __shared__ short8 stgv[2][640];          // 20 KB
    __shared__ float  sq1buf[64][17];
    __shared__ float  sq2buf[4][96];
    __shared__ float  outT[NO][68];

    const int sx   = (int)blockIdx.x;              // 0..63 tile slot
    const int tile = (sx & 7) * 8 + (sx >> 3);     // XCD swizzle: 8 contiguous
    const int b    = (int)blockIdx.y;              // tiles per XCD
    const int cs   = (int)blockIdx.z;
    const int t0   = tile * 64;

    const int tid  = (int)threadIdx.x;
    const int lane = tid & 63;
    const int w    = tid >> 6;                     // wave id = M-tile id

    // ---- staging maps (constant across chunks) ----
    const int u1 = tid & 15;                       // f1 t-run (4 cols)
    const int q1 = tid >> 4;                       // f1 c-pair: rows 2q1,2q1+1
    const int r2 = tid & 15;                       // f2 window run (4 cols)
    const int q2 = tid >> 4;                       // f2 c-pair
    const bool x2 = (r2 < 8);                      // also stages run 16+r2

    const float* f1p = f1 + ((size_t)b * C + cs * CPS + 2 * q1) * T + t0 + 4 * u1;
    const float* f2p = f2 + ((size_t)b * C + cs * CPS + 2 * q2) * T;
    const int cA = min(max(t0 - 16 + 4 * r2,        0), T - 4);  // clamped src
    const int cB = min(max(t0 - 16 + 4 * (16 + r2), 0), T - 4);

    // store hw offsets: tile=[16t][32c], elem(t,c) at t*32 + slot'*8 + (c&7),
    // slot' = ((c>>3) + (t>>2)) & 3. Writes step +32 hw per t (i=0..3).
    const int f1hw = (u1 >> 2) * 512 + 4 * (u1 & 3) * 32
                   + ((((q1 >> 2) + (u1 & 3)) & 3) << 3) + 2 * (q1 & 3);
    const int f2hwA = 2048 + (r2 >> 2) * 512 + 4 * (r2 & 3) * 32
                    + ((((q2 >> 2) + (r2 & 3)) & 3) << 3) + 2 * (q2 & 3);
    const int f2hwB = f2hwA + 2048;               // run 16+r2: tile +4

    // fragment read offset: lane wants t=lane&15, c-slot=lane>>4
    const int ft  = lane & 15;
    const int fhw = ft * 32 + ((((lane >> 4) + (ft >> 2)) & 3) << 3);

    float sq1[4]  = {0.f, 0.f, 0.f, 0.f};
    float sq2a[4] = {0.f, 0.f, 0.f, 0.f};
    float sq2b[4] = {0.f, 0.f, 0.f, 0.f};
    f32x4 acc0 = {0.f,0.f,0.f,0.f}, acc1 = {0.f,0.f,0.f,0.f}, acc2 = {0.f,0.f,0.f,0.f};

    auto load_chunk = [&](int k) {
        Regs r; const size_t o = (size_t)k * 32 * T;
        r.a0  = *(const float4*)(f1p + o);
        r.a1  = *(const float4*)(f1p + o + T);
        r.b0  = *(const float4*)(f2p + o + cA);
        r.b0b = *(const float4*)(f2p + o + cA + T);
        if (x2) {
            r.b1  = *(const float4*)(f2p + o + cB);
            r.b1b = *(const float4*)(f2p + o + cB + T);
        }
        return r;
    };
    auto commit = [&](const Regs& r, int buf) {
        unsigned short* S = (unsigned short*)&stgv[buf][0];
        const float* a0 = (const float*)&r.a0;  const float* a1  = (const float*)&r.a1;
        const float* b0 = (const float*)&r.b0;  const float* b0b = (const float*)&r.b0b;
        const float* b1 = (const float*)&r.b1;  const float* b1b = (const float*)&r.b1b;
#pragma unroll
        for (int i = 0; i < 4; ++i) {
            *(unsigned*)&S[f1hw  + 32 * i] = pack2(a0[i], a1[i]);
            *(unsigned*)&S[f2hwA + 32 * i] = pack2(b0[i], b0b[i]);
            sq1[i]  += a0[i] * a0[i] + a1[i] * a1[i];
            sq2a[i] += b0[i] * b0[i] + b0b[i] * b0b[i];
        }
        if (x2) {
#pragma unroll
            for (int i = 0; i < 4; ++i) {
                *(unsigned*)&S[f2hwB + 32 * i] = pack2(b1[i], b1b[i]);
                sq2b[i] += b1[i] * b1[i] + b1b[i] * b1b[i];
            }
        }
    };
    auto compute = [&](int buf) {
        const unsigned short* S = (const unsigned short*)&stgv[buf][0];
        short8 af  = *(const short8*)&S[w * 512 + fhw];
        short8 bf0 = *(const short8*)&S[2048 + (w + 0) * 512 + fhw];
        short8 bf1 = *(const short8*)&S[2048 + (w + 1) * 512 + fhw];
        short8 bf2 = *(const short8*)&S[2048 + (w + 2) * 512 + fhw];
        acc0 = __builtin_amdgcn_mfma_f32_16x16x32_bf16(af, bf0, acc0, 0, 0, 0);
        acc1 = __builtin_amdgcn_mfma_f32_16x16x32_bf16(af, bf1, acc1, 0, 0, 0);
        acc2 = __builtin_amdgcn_mfma_f32_16x16x32_bf16(af, bf2, acc2, 0, 0, 0);
    };

    // ---- depth-2 pipelined K-loop, double-buffered LDS (verified) ----
    Regs RA = load_chunk(0), RB = load_chunk(1);
    for (int k = 0; k < NCHK; k += 2) {
        commit(RA, 0);
        __syncthreads();
        if (k + 2 < NCHK) RA = load_chunk(k + 2);
        compute(0);
        commit(RB, 1);
        __syncthreads();
        if (k + 3 < NCHK) RB = load_chunk(k + 3);
        compute(1);
    }

    // ---- sum-of-squares partials -> workspace ----
#pragma unroll
    for (int e = 0; e < 4; ++e) sq1buf[4 * u1 + e][q1] = sq1[e];
#pragma unroll
    for (int i = 0; i < 4; ++i) {
        sq2a[i] += __shfl_xor(sq2a[i], 16, 64);
        sq2a[i] += __shfl_xor(sq2a[i], 32, 64);
        sq2b[i] += __shfl_xor(sq2b[i], 16, 64);
        sq2b[i] += __shfl_xor(sq2b[i], 32, 64);
    }
    if (lane < 16) {
#pragma unroll
        for (int i = 0; i < 4; ++i) sq2buf[w][4 * lane + i] = sq2a[i];
    }
    if (lane < 8) {
#pragma unroll
        for (int i = 0; i < 4; ++i) sq2buf[w][64 + 4 * lane + i] = sq2b[i];
    }
    __syncthreads();
    if (tid < 64) {
        float s = 0.f;
#pragma unroll
        for (int g = 0; g < 16; ++g) s += sq1buf[tid][g];
        s1p[((size_t)cs * B + b) * T + t0 + tid] = s;
    } else if (tid < 160) {
        const int f = tid - 64;
        float s = sq2buf[0][f] + sq2buf[1][f] + sq2buf[2][f] + sq2buf[3][f];
        if (f >= 16 && f < 80)
            s2p[((size_t)cs * B + b) * T + t0 + f - 16] = s;
    }

    // ---- epilogue: raw band elems -> outT, then coalesced partial-dot store ----
    const int m0  = t0 + w * 16;
    const int cr  = lane & 15;            // N-col within tile
    const int rr4 = (lane >> 4) * 4;      // M-row base
#define EPI(nt, A)                                                          \
    {                                                                       \
        const int tp = t0 - 16 + (w + (nt)) * 16 + cr;                      \
        _Pragma("unroll")                                                   \
        for (int r = 0; r < 4; ++r) {                                       \
            const int t = m0 + rr4 + r;                                     \
            const int d = tp - t;                                           \
            if (tp >= 0 && tp < T && d >= -MD && d <= MD)                   \
                outT[d + MD][t - t0] = (A)[r];                              \
        }                                                                   \
    }
    EPI(0, acc0) EPI(1, acc1) EPI(2, acc2)
#undef EPI
    __syncthreads();

    for (int task = tid; task < NO * 16; task += 256) {
        const int o  = task >> 4;
        const int t4 = (task & 15) * 4;
        const float4 v = *(const float4*)&outT[o][t4];
        *(float4*)(dots + (((size_t)cs * B + b) * NO + o) * T + t0 + t4) = v;
    }
}

// ---------------------------------------------------------------------------
// Finalize: reduce CS partials, compute inv-norms (LDS halo for t'), apply
// clamp-redirect replication, write normalized output. 128 blocks x 256 thr.
// ---------------------------------------------------------------------------
__global__ __launch_bounds__(256)
void corr_fin(const float* __restrict__ dots, const float* __restrict__ s1p,
              const float* __restrict__ s2p, float* __restrict__ out)
{
    __shared__ float inv2s[276];
    const int bx  = (int)blockIdx.x;
    const int b   = bx >> 4;
    const int tc  = (bx & 15) * 256;
    const int tid = (int)threadIdx.x;
    const int t   = tc + tid;

    auto inv_of = [&](const float* p, int tt) {
        float s = 0.f;
#pragma unroll
        for (int cs = 0; cs < CS; ++cs) s += p[((size_t)cs * B + b) * T + tt];
        return 1.f / fmaxf(sqrtf(s), 1e-12f);
    };

    const float i1 = inv_of(s1p, t);
    inv2s[10 + tid] = inv_of(s2p, t);
    if (tid < 10) {
        const int tl = max(tc - 10 + tid, 0);
        inv2s[tid] = inv_of(s2p, tl);
    }
    if (tid >= 246) {
        const int tr = min(tc + 256 + (tid - 246), T - 1);
        inv2s[266 + (tid - 246)] = inv_of(s2p, tr);
    }
    __syncthreads();

#pragma unroll
    for (int o = 0; o < NO; ++o) {
        const int tp = min(max(t + o - MD, 0), T - 1);
        const int o2 = tp - t + MD;                  // redirected (valid) slot
        float s = 0.f;
#pragma unroll
        for (int cs = 0; cs < CS; ++cs)
            s += dots[(((size_t)cs * B + b) * NO + o2) * T + t];
        out[((size_t)b * NO + o) * T + t] = s * i1 * inv2s[10 + (tp - tc)];
    }
}

extern "C" void kernel_launch(void* const* d_in, const int* in_sizes, int n_in,
                              void* d_out, int out_size, void* d_ws, size_t ws_size,
                              hipStream_t stream)
{
    const float* f1 = (const float*)d_in[0];
    const float* f2 = (const float*)d_in[1];
    float* wsf  = (float*)d_ws;
    float* dots = wsf;                                   // CS*B*NO*T floats
    float* s1p  = dots + (size_t)CS * B * NO * T;        // CS*B*T
    float* s2p  = s1p  + (size_t)CS * B * T;             // CS*B*T  (12.1 MB total)
    (void)ws_size;

    corr_mfma<<<dim3(64, 8, CS), dim3(256), 0, stream>>>(f1, f2, dots, s1p, s2p);
    corr_fin<<<dim3(128), dim3(256), 0, stream>>>(dots, s1p, s2p, (float*)d_out);
}